// Round 2
// baseline (276.064 us; speedup 1.0000x reference)
//
#include <hip/hip_runtime.h>

typedef __attribute__((ext_vector_type(8))) short short8;
typedef __attribute__((ext_vector_type(4))) float floatx4;

#define DMODEL 1024
#define NHEAD  16
#define DK     64
#define SEQ    2048

__device__ __forceinline__ unsigned short f2bf(float f) {
  unsigned u = __builtin_bit_cast(unsigned, f);
  u += 0x7FFF + ((u >> 16) & 1);   // RTNE
  return (unsigned short)(u >> 16);
}

__global__ void f2bf_kernel(const float* __restrict__ in, unsigned short* __restrict__ out, int n4) {
  int i = blockIdx.x * 256 + threadIdx.x;
  int stride = gridDim.x * 256;
  for (; i < n4; i += stride) {
    float4 v = reinterpret_cast<const float4*>(in)[i];
    ushort4 o;
    o.x = f2bf(v.x); o.y = f2bf(v.y); o.z = f2bf(v.z); o.w = f2bf(v.w);
    reinterpret_cast<ushort4*>(out)[i] = o;
  }
}

__device__ __forceinline__ void gload16(const void* g, void* l) {
  __builtin_amdgcn_global_load_lds((const __attribute__((address_space(1))) void*)g,
                                   (__attribute__((address_space(3))) void*)l, 16, 0, 0);
}

// C = A[M][K] (bf16) * Bt[N][K]^T (bf16) + bias.
// MODE 0: scatter bf16 to Q[b,h,s,d], K[b,h,s,d], Vt[b,h,d,s].  MODE 1: fp32 C out.
template<int MODE>
__global__ __launch_bounds__(256)
void gemm_bt(const unsigned short* __restrict__ A, const unsigned short* __restrict__ Bt,
             const float* __restrict__ bias, float* __restrict__ Cf,
             unsigned short* __restrict__ Qo, unsigned short* __restrict__ Ko,
             unsigned short* __restrict__ Vto, int M, int N, int K)
{
  __shared__ short Al[128 * 32];
  __shared__ short Bl[128 * 32];
  const int tid = threadIdx.x, lane = tid & 63, wave = tid >> 6;
  const int wr = wave >> 1, wc = wave & 1;
  const int m0 = blockIdx.x * 128, n0 = blockIdx.y * 128;

  floatx4 z4 = {0.f, 0.f, 0.f, 0.f};
  floatx4 acc[4][4];
#pragma unroll
  for (int i = 0; i < 4; i++)
#pragma unroll
    for (int j = 0; j < 4; j++) acc[i][j] = z4;

  for (int k0 = 0; k0 < K; k0 += 32) {
    __syncthreads();
#pragma unroll
    for (int i = 0; i < 2; i++) {
      int chunk = wave * 2 + i;                  // 0..7
      int e = chunk * 512 + lane * 8;            // element index into 128x32 tile
      int row = e >> 5, kc = e & 31;
      gload16(A  + (size_t)(m0 + row) * K + k0 + kc, &Al[chunk * 512]);
      gload16(Bt + (size_t)(n0 + row) * K + k0 + kc, &Bl[chunk * 512]);
    }
    __syncthreads();
    short8 af[4], bfr[4];
#pragma unroll
    for (int i = 0; i < 4; i++) {
      af[i]  = *reinterpret_cast<const short8*>(&Al[(wr * 64 + i * 16 + (lane & 15)) * 32 + ((lane >> 4) << 3)]);
      bfr[i] = *reinterpret_cast<const short8*>(&Bl[(wc * 64 + i * 16 + (lane & 15)) * 32 + ((lane >> 4) << 3)]);
    }
#pragma unroll
    for (int i = 0; i < 4; i++)
#pragma unroll
      for (int j = 0; j < 4; j++)
        acc[i][j] = __builtin_amdgcn_mfma_f32_16x16x32_bf16(af[i], bfr[j], acc[i][j], 0, 0, 0);
  }

#pragma unroll
  for (int i = 0; i < 4; i++) {
#pragma unroll
    for (int j = 0; j < 4; j++) {
#pragma unroll
      for (int r = 0; r < 4; r++) {
        int m = m0 + wr * 64 + i * 16 + ((lane >> 4) << 2) + r;  // C row = (lane>>4)*4+reg
        int n = n0 + wc * 64 + j * 16 + (lane & 15);             // C col = lane&15
        float v = acc[i][j][r] + bias[n];
        if (MODE == 1) {
          Cf[(size_t)m * N + n] = v;
        } else {
          int which = n >> 10;
          int h = (n & 1023) >> 6;
          int d = n & 63;
          int b = m >> 11, s = m & 2047;
          int bh = (b << 4) + h;
          unsigned short bv = f2bf(v);
          if (which == 0)      Qo[((size_t)bh * SEQ + s) * DK + d] = bv;
          else if (which == 1) Ko[((size_t)bh * SEQ + s) * DK + d] = bv;
          else                 Vto[((size_t)bh * DK + d) * SEQ + s] = bv;
        }
      }
    }
  }
}

// Flash attention: grid (16 q-tiles, 32 bh), 256 threads = 4 waves.
// Each wave owns row-blocks {wave, wave+4} (16 rows each) of the 128-row q-tile.
__global__ __launch_bounds__(256)
void attn_kernel(const unsigned short* __restrict__ Qb, const unsigned short* __restrict__ Kb,
                 const unsigned short* __restrict__ Vtb, unsigned short* __restrict__ AO)
{
  __shared__ short Kl[64 * 64];        // [kv][dk], XOR-swizzled
  __shared__ short Vl[64 * 64];        // [dk][kv], XOR-swizzled
  __shared__ short Pl[4][32 * 64];     // per-wave P staging, XOR-swizzled
  const int tid = threadIdx.x, lane = tid & 63, wave = tid >> 6;
  const int qt = blockIdx.x, bh = blockIdx.y;
  const int b = bh >> 4, h = bh & 15;
  const int q0 = qt * 128;
  const unsigned short* Qh = Qb  + (size_t)bh * SEQ * DK;
  const unsigned short* Kh = Kb  + (size_t)bh * SEQ * DK;
  const unsigned short* Vh = Vtb + (size_t)bh * DK * SEQ;
  short* Pw = Pl[wave];

  // Q fragments in registers: [rowblk][kslice]
  short8 qf[2][2];
#pragma unroll
  for (int rb = 0; rb < 2; rb++) {
    int row = q0 + (rb * 4 + wave) * 16 + (lane & 15);
#pragma unroll
    for (int ks = 0; ks < 2; ks++)
      qf[rb][ks] = *reinterpret_cast<const short8*>(&Qh[(size_t)row * DK + ks * 32 + ((lane >> 4) << 3)]);
  }

  floatx4 z4 = {0.f, 0.f, 0.f, 0.f};
  floatx4 o[2][4];
  float m_[2][4], l_[2][4];
#pragma unroll
  for (int rb = 0; rb < 2; rb++) {
#pragma unroll
    for (int db = 0; db < 4; db++) o[rb][db] = z4;
#pragma unroll
    for (int r = 0; r < 4; r++) { m_[rb][r] = -1e30f; l_[rb][r] = 0.f; }
  }

  const int kv_stop = q0 + 128;
  for (int kv0 = 0; kv0 < kv_stop; kv0 += 64) {
    __syncthreads();
    // stage K tile [64][64] and Vt tile [64][64], swizzled
    for (int i = tid; i < 512; i += 256) {
      int row = i >> 3, c8 = (i & 7) << 3;
      short8 kvv = *reinterpret_cast<const short8*>(&Kh[(size_t)(kv0 + row) * DK + c8]);
      *reinterpret_cast<short8*>(&Kl[(row * 64 + c8) ^ ((row & 7) << 3)]) = kvv;
      short8 vvv = *reinterpret_cast<const short8*>(&Vh[(size_t)row * SEQ + kv0 + c8]);
      *reinterpret_cast<short8*>(&Vl[(row * 64 + c8) ^ ((row & 7) << 3)]) = vvv;
    }
    __syncthreads();

#pragma unroll
    for (int rb = 0; rb < 2; rb++) {
      // scores: 4 kv-blocks x 2 k-slices
      floatx4 sc[4];
#pragma unroll
      for (int nb = 0; nb < 4; nb++) sc[nb] = z4;
#pragma unroll
      for (int ks = 0; ks < 2; ks++) {
#pragma unroll
        for (int nb = 0; nb < 4; nb++) {
          int kvr = nb * 16 + (lane & 15);
          short8 kf = *reinterpret_cast<const short8*>(
              &Kl[(kvr * 64 + ks * 32 + ((lane >> 4) << 3)) ^ ((kvr & 7) << 3)]);
          sc[nb] = __builtin_amdgcn_mfma_f32_16x16x32_bf16(qf[rb][ks], kf, sc[nb], 0, 0, 0);
        }
      }
      // scale + causal mask + row max
      float sv[4][4];
      float mx[4] = {-1e30f, -1e30f, -1e30f, -1e30f};
#pragma unroll
      for (int nb = 0; nb < 4; nb++) {
#pragma unroll
        for (int r = 0; r < 4; r++) {
          int kv = kv0 + nb * 16 + (lane & 15);
          int qr = q0 + (rb * 4 + wave) * 16 + ((lane >> 4) << 2) + r;
          float x_ = sc[nb][r] * 0.125f;
          x_ = (kv <= qr) ? x_ : -1e30f;
          sv[nb][r] = x_;
          mx[r] = fmaxf(mx[r], x_);
        }
      }
#pragma unroll
      for (int msk = 1; msk < 16; msk <<= 1)
#pragma unroll
        for (int r = 0; r < 4; r++) mx[r] = fmaxf(mx[r], __shfl_xor(mx[r], msk));
      float alpha[4];
#pragma unroll
      for (int r = 0; r < 4; r++) {
        float mn = fmaxf(m_[rb][r], mx[r]);
        alpha[r] = __expf(m_[rb][r] - mn);
        m_[rb][r] = mn;
      }
      float rs[4] = {0.f, 0.f, 0.f, 0.f};
#pragma unroll
      for (int nb = 0; nb < 4; nb++) {
#pragma unroll
        for (int r = 0; r < 4; r++) {
          float p = __expf(sv[nb][r] - m_[rb][r]);
          rs[r] += p;
          int lr = rb * 16 + ((lane >> 4) << 2) + r;
          int col = nb * 16 + (lane & 15);
          Pw[(lr * 64 + col) ^ ((lr & 7) << 3)] = (short)f2bf(p);
        }
      }
#pragma unroll
      for (int msk = 1; msk < 16; msk <<= 1)
#pragma unroll
        for (int r = 0; r < 4; r++) rs[r] += __shfl_xor(rs[r], msk);
#pragma unroll
      for (int r = 0; r < 4; r++) l_[rb][r] = l_[rb][r] * alpha[r] + rs[r];
#pragma unroll
      for (int db = 0; db < 4; db++)
#pragma unroll
        for (int r = 0; r < 4; r++) o[rb][db][r] *= alpha[r];
    }

    // PV: o += P * V   (P per-wave in LDS; DS ops in-order within wave)
#pragma unroll
    for (int rb = 0; rb < 2; rb++) {
#pragma unroll
      for (int ks2 = 0; ks2 < 2; ks2++) {
        int lr = rb * 16 + (lane & 15);
        short8 pf = *reinterpret_cast<const short8*>(
            &Pw[(lr * 64 + ks2 * 32 + ((lane >> 4) << 3)) ^ ((lr & 7) << 3)]);
#pragma unroll
        for (int db = 0; db < 4; db++) {
          int dr = db * 16 + (lane & 15);
          short8 vf = *reinterpret_cast<const short8*>(
              &Vl[(dr * 64 + ks2 * 32 + ((lane >> 4) << 3)) ^ ((dr & 7) << 3)]);
          o[rb][db] = __builtin_amdgcn_mfma_f32_16x16x32_bf16(pf, vf, o[rb][db], 0, 0, 0);
        }
      }
    }
  }

  // normalize + write attn out as bf16 [B,S,H*DK]
#pragma unroll
  for (int rb = 0; rb < 2; rb++) {
#pragma unroll
    for (int db = 0; db < 4; db++) {
#pragma unroll
      for (int r = 0; r < 4; r++) {
        int q = q0 + (rb * 4 + wave) * 16 + ((lane >> 4) << 2) + r;
        int d = db * 16 + (lane & 15);
        float val = o[rb][db][r] / l_[rb][r];
        AO[((size_t)(b * SEQ + q)) * DMODEL + h * DK + d] = f2bf(val);
      }
    }
  }
}

extern "C" void kernel_launch(void* const* d_in, const int* in_sizes, int n_in,
                              void* d_out, int out_size, void* d_ws, size_t ws_size,
                              hipStream_t stream) {
  (void)in_sizes; (void)n_in; (void)out_size; (void)ws_size;
  const float* x     = (const float*)d_in[0];
  const float* w_qkv = (const float*)d_in[1];
  const float* b_qkv = (const float*)d_in[2];
  const float* w_out = (const float*)d_in[3];
  const float* b_out = (const float*)d_in[4];
  float* out = (float*)d_out;

  char* ws = (char*)d_ws;
  unsigned short* xb    = (unsigned short*)(ws);                    // 8 MB   [4096][1024]
  unsigned short* wqkvb = (unsigned short*)(ws + (8u << 20));       // 6 MB   [3072][1024]
  unsigned short* woutb = (unsigned short*)(ws + (14u << 20));      // 2 MB   [1024][1024]
  unsigned short* Qb    = (unsigned short*)(ws + (16u << 20));      // 8 MB   [32][2048][64]
  unsigned short* Kb    = (unsigned short*)(ws + (24u << 20));      // 8 MB   [32][2048][64]
  unsigned short* Vtb   = (unsigned short*)(ws + (32u << 20));      // 8 MB   [32][64][2048]
  unsigned short* AOb   = (unsigned short*)(ws + (40u << 20));      // 8 MB   [4096][1024]

  f2bf_kernel<<<2048, 256, 0, stream>>>(x,     xb,    4194304 / 4);
  f2bf_kernel<<<2048, 256, 0, stream>>>(w_qkv, wqkvb, 3145728 / 4);
  f2bf_kernel<<<1024, 256, 0, stream>>>(w_out, woutb, 1048576 / 4);

  gemm_bt<0><<<dim3(32, 24), 256, 0, stream>>>(xb, wqkvb, b_qkv, nullptr,
                                               Qb, Kb, Vtb, 4096, 3072, 1024);

  attn_kernel<<<dim3(16, 32), 256, 0, stream>>>(Qb, Kb, Vtb, AOb);

  gemm_bt<1><<<dim3(32, 8), 256, 0, stream>>>(AOb, woutb, b_out, out,
                                              nullptr, nullptr, nullptr, 4096, 1024, 1024);
}

// Round 4
// 211.795 us; speedup vs baseline: 1.3034x; 1.3034x over previous
//
#include <hip/hip_runtime.h>

typedef __attribute__((ext_vector_type(8))) short short8;
typedef __attribute__((ext_vector_type(4))) float floatx4;

#define DMODEL 1024
#define NHEAD  16
#define DK     64
#define SEQ    2048
#define QSCALE 0.18033688011112042f   // 0.125 * log2(e): folded into Q so scores are in log2 domain

__device__ __forceinline__ unsigned short f2bf(float f) {
  unsigned u = __builtin_bit_cast(unsigned, f);
  u += 0x7FFF + ((u >> 16) & 1);   // RTNE
  return (unsigned short)(u >> 16);
}

__global__ void f2bf_kernel(const float* __restrict__ in, unsigned short* __restrict__ out, int n4) {
  int i = blockIdx.x * 256 + threadIdx.x;
  int stride = gridDim.x * 256;
  for (; i < n4; i += stride) {
    float4 v = reinterpret_cast<const float4*>(in)[i];
    ushort4 o;
    o.x = f2bf(v.x); o.y = f2bf(v.y); o.z = f2bf(v.z); o.w = f2bf(v.w);
    reinterpret_cast<ushort4*>(out)[i] = o;
  }
}

__device__ __forceinline__ void gload16(const void* g, void* l) {
  __builtin_amdgcn_global_load_lds((const __attribute__((address_space(1))) void*)g,
                                   (__attribute__((address_space(3))) void*)l, 16, 0, 0);
}

// C = A[M][K] (bf16) * Bt[N][K]^T (bf16) + bias.
// MODE 0: scatter bf16 to Q (pre-scaled by QSCALE), K, Vrow — all [bh][s][64].
// MODE 1: fp32 C out.
// Double-buffered LDS, single barrier per K-step, prologue stage.
template<int MODE>
__global__ __launch_bounds__(256)
void gemm_bt(const unsigned short* __restrict__ A, const unsigned short* __restrict__ Bt,
             const float* __restrict__ bias, float* __restrict__ Cf,
             unsigned short* __restrict__ Qo, unsigned short* __restrict__ Ko,
             unsigned short* __restrict__ Vro, int M, int N, int K)
{
  __shared__ short Al[2][128 * 32];
  __shared__ short Bl[2][128 * 32];
  const int tid = threadIdx.x, lane = tid & 63, wave = tid >> 6;
  const int wr = wave >> 1, wc = wave & 1;
  const int m0 = blockIdx.x * 128, n0 = blockIdx.y * 128;

  floatx4 z4 = {0.f, 0.f, 0.f, 0.f};
  floatx4 acc[4][4];
#pragma unroll
  for (int i = 0; i < 4; i++)
#pragma unroll
    for (int j = 0; j < 4; j++) acc[i][j] = z4;

  auto STAGE = [&](int sb, int k0) {
#pragma unroll
    for (int i = 0; i < 2; i++) {
      int chunk = wave * 2 + i;                  // 0..7
      int e = chunk * 512 + lane * 8;            // element index into 128x32 tile
      int row = e >> 5, kc = e & 31;
      gload16(A  + (size_t)(m0 + row) * K + k0 + kc, &Al[sb][chunk * 512]);
      gload16(Bt + (size_t)(n0 + row) * K + k0 + kc, &Bl[sb][chunk * 512]);
    }
  };

  STAGE(0, 0);
  int buf = 0;
  for (int k0 = 0; k0 < K; k0 += 32) {
    __syncthreads();                              // stage for this k0 complete (vmcnt drained)
    if (k0 + 32 < K) STAGE(buf ^ 1, k0 + 32);     // prefetch next tile (hidden under compute)
    const short* Ac = Al[buf];
    const short* Bc = Bl[buf];
    short8 af[4], bfr[4];
#pragma unroll
    for (int i = 0; i < 4; i++) {
      af[i]  = *reinterpret_cast<const short8*>(&Ac[(wr * 64 + i * 16 + (lane & 15)) * 32 + ((lane >> 4) << 3)]);
      bfr[i] = *reinterpret_cast<const short8*>(&Bc[(wc * 64 + i * 16 + (lane & 15)) * 32 + ((lane >> 4) << 3)]);
    }
#pragma unroll
    for (int i = 0; i < 4; i++)
#pragma unroll
      for (int j = 0; j < 4; j++)
        acc[i][j] = __builtin_amdgcn_mfma_f32_16x16x32_bf16(af[i], bfr[j], acc[i][j], 0, 0, 0);
    buf ^= 1;
  }

#pragma unroll
  for (int i = 0; i < 4; i++) {
#pragma unroll
    for (int j = 0; j < 4; j++) {
#pragma unroll
      for (int r = 0; r < 4; r++) {
        int m = m0 + wr * 64 + i * 16 + ((lane >> 4) << 2) + r;  // C row = (lane>>4)*4+reg
        int n = n0 + wc * 64 + j * 16 + (lane & 15);             // C col = lane&15
        float v = acc[i][j][r] + bias[n];
        if (MODE == 1) {
          Cf[(size_t)m * N + n] = v;
        } else {
          int which = n >> 10;
          int h = (n & 1023) >> 6;
          int d = n & 63;
          int b = m >> 11, s = m & 2047;
          int bh = (b << 4) + h;
          size_t idx = ((size_t)bh * SEQ + s) * DK + d;
          if (which == 0)      Qo[idx]  = f2bf(v * QSCALE);
          else if (which == 1) Ko[idx]  = f2bf(v);
          else                 Vro[idx] = f2bf(v);
        }
      }
    }
  }
}

// V row-major [bh][s][64] -> Vt [bh][64][s], LDS-tiled, coalesced both sides.
__global__ __launch_bounds__(256)
void transpose_v(const unsigned short* __restrict__ Vr, unsigned short* __restrict__ Vt) {
  __shared__ unsigned short T[64][68];   // +4 pad; row stride 136B (8B-aligned)
  const int tid = threadIdx.x;
  const int bh = blockIdx.x, st = blockIdx.y;
  const int s0 = st * 64;
  const unsigned short* src = Vr + ((size_t)bh * SEQ + s0) * DK;
#pragma unroll
  for (int i = 0; i < 4; i++) {
    int idx = tid + 256 * i;
    int row = idx >> 4, c = (idx & 15) << 2;
    ushort4 v = *reinterpret_cast<const ushort4*>(&src[row * DK + c]);
    *reinterpret_cast<ushort4*>(&T[row][c]) = v;
  }
  __syncthreads();
  unsigned short* dst = Vt + (size_t)bh * DK * SEQ + s0;
#pragma unroll
  for (int i = 0; i < 4; i++) {
    int idx = tid + 256 * i;
    int d = idx >> 4, sc = (idx & 15) << 2;
    ushort4 o;
    o.x = T[sc + 0][d]; o.y = T[sc + 1][d]; o.z = T[sc + 2][d]; o.w = T[sc + 3][d];
    *reinterpret_cast<ushort4*>(&dst[(size_t)d * SEQ + sc]) = o;
  }
}

// Flash attention: grid (32 bh, 16 y), 512 threads = 8 waves; QBLK=128 (wave w owns 16 rows).
// Balanced qt map: y<8 -> y, else 23-y (pairs high/low work per CU).
// K/V double-buffered via global_load_lds (linear dest, pre-swizzled source, swizzled read).
__global__ __launch_bounds__(512)
void attn_kernel(const unsigned short* __restrict__ Qb, const unsigned short* __restrict__ Kb,
                 const unsigned short* __restrict__ Vtb, unsigned short* __restrict__ AO)
{
  __shared__ short Kl[2][4096];       // [kv 64][dk 64] XOR-swizzled
  __shared__ short Vl[2][4096];       // [dk 64][kv 64] XOR-swizzled
  __shared__ short Pl[8][1024];       // per-wave P [16][64] XOR-swizzled
  const int tid = threadIdx.x, lane = tid & 63, wave = tid >> 6;
  const int bh = blockIdx.x;
  const int y = blockIdx.y;
  const int qt = (y < 8) ? y : (23 - y);
  const int b = bh >> 4, h = bh & 15;
  const int q0 = qt * 128;
  const int qrow_w = q0 + wave * 16;
  const int qlast = qrow_w + 15;
  const unsigned short* Qh = Qb  + (size_t)bh * SEQ * DK;
  const unsigned short* Kh = Kb  + (size_t)bh * SEQ * DK;
  const unsigned short* Vh = Vtb + (size_t)bh * DK * SEQ;
  short* Pw = Pl[wave];

  // Q fragments (already scaled by QSCALE in GEMM)
  short8 qf[2];
  {
    int arow = qrow_w + (lane & 15);
#pragma unroll
    for (int ks = 0; ks < 2; ks++)
      qf[ks] = *reinterpret_cast<const short8*>(&Qh[(size_t)arow * DK + ks * 32 + ((lane >> 4) << 3)]);
  }

  floatx4 z4 = {0.f, 0.f, 0.f, 0.f};
  floatx4 o[4];
  float m_[4], l_[4];
#pragma unroll
  for (int db = 0; db < 4; db++) o[db] = z4;
#pragma unroll
  for (int r = 0; r < 4; r++) { m_[r] = -1e30f; l_[r] = 0.f; }

  // staging: each wave stages 8 rows (512 elems) of K and V; source col pre-swizzled
  const int srow = lane >> 3;                       // row within wave's 8-row chunk
  const int srk  = ((lane & 7) ^ srow) << 3;        // swizzled source col (row&7 == srow)
  auto STAGE = [&](int sb, int kv0) {
    int row = wave * 8 + srow;
    gload16(Kh + (size_t)(kv0 + row) * DK + srk, &Kl[sb][wave * 512]);
    gload16(Vh + (size_t)row * SEQ + kv0 + srk,  &Vl[sb][wave * 512]);
  };

  const int ntiles = 2 * qt + 2;
  STAGE(0, 0);
  int buf = 0;
  for (int it = 0; it < ntiles; it++) {
    __syncthreads();                                   // tile `it` staged (vmcnt drained)
    if (it + 1 < ntiles) STAGE(buf ^ 1, (it + 1) * 64);
    const short* Kc = Kl[buf];
    const short* Vc = Vl[buf];
    buf ^= 1;
    const int kv0 = it * 64;
    if (kv0 > qlast) continue;                         // fully masked for this wave

    const bool masked = (kv0 + 63 > qrow_w);

    // QK^T
    floatx4 sc[4];
#pragma unroll
    for (int nb = 0; nb < 4; nb++) sc[nb] = z4;
#pragma unroll
    for (int ks = 0; ks < 2; ks++) {
#pragma unroll
      for (int nb = 0; nb < 4; nb++) {
        int kvr = nb * 16 + (lane & 15);
        short8 kf = *reinterpret_cast<const short8*>(
            &Kc[((kvr << 6) + ks * 32 + ((lane >> 4) << 3)) ^ ((kvr & 7) << 3)]);
        sc[nb] = __builtin_amdgcn_mfma_f32_16x16x32_bf16(qf[ks], kf, sc[nb], 0, 0, 0);
      }
    }

    // mask (diagonal tiles only) + row max
    float sv[4][4];
    const int lrb = (lane >> 4) << 2;
#pragma unroll
    for (int nb = 0; nb < 4; nb++)
#pragma unroll
      for (int r = 0; r < 4; r++) sv[nb][r] = sc[nb][r];
    if (masked) {
      int kvb = kv0 + (lane & 15);
      int qr = qrow_w + lrb;
#pragma unroll
      for (int nb = 0; nb < 4; nb++)
#pragma unroll
        for (int r = 0; r < 4; r++)
          sv[nb][r] = (kvb + nb * 16 <= qr + r) ? sv[nb][r] : -1e30f;
    }
    float mx4[4] = {-1e30f, -1e30f, -1e30f, -1e30f};
#pragma unroll
    for (int nb = 0; nb < 4; nb++)
#pragma unroll
      for (int r = 0; r < 4; r++) mx4[r] = fmaxf(mx4[r], sv[nb][r]);
#pragma unroll
    for (int msk = 1; msk < 16; msk <<= 1)
#pragma unroll
      for (int r = 0; r < 4; r++) mx4[r] = fmaxf(mx4[r], __shfl_xor(mx4[r], msk));

    // deferred rescale (T13): only when max grows > 8 (log2 domain); P then bounded by 256
    float nm[4]; bool need = false;
#pragma unroll
    for (int r = 0; r < 4; r++) { nm[r] = fmaxf(m_[r], mx4[r]); need = need || (nm[r] - m_[r] > 8.0f); }
    if (__any(need)) {
#pragma unroll
      for (int r = 0; r < 4; r++) {
        float al = __builtin_amdgcn_exp2f(m_[r] - nm[r]);
        m_[r] = nm[r];
        l_[r] *= al;
#pragma unroll
        for (int db = 0; db < 4; db++) o[db][r] *= al;
      }
    }

    // P = exp2(sv - m), truncated to bf16 consistently for numerator and denominator
    float rs4[4] = {0.f, 0.f, 0.f, 0.f};
#pragma unroll
    for (int nb = 0; nb < 4; nb++)
#pragma unroll
      for (int r = 0; r < 4; r++) {
        float p = __builtin_amdgcn_exp2f(sv[nb][r] - m_[r]);
        unsigned pu = __builtin_bit_cast(unsigned, p);
        rs4[r] += __builtin_bit_cast(float, pu & 0xffff0000u);
        int lr = lrb + r;
        Pw[((lr << 6) + nb * 16 + (lane & 15)) ^ ((lr & 7) << 3)] = (short)(pu >> 16);
      }
#pragma unroll
    for (int msk = 1; msk < 16; msk <<= 1)
#pragma unroll
      for (int r = 0; r < 4; r++) rs4[r] += __shfl_xor(rs4[r], msk);
#pragma unroll
    for (int r = 0; r < 4; r++) l_[r] += rs4[r];

    // PV: o += P * V
#pragma unroll
    for (int ks2 = 0; ks2 < 2; ks2++) {
      int lr = lane & 15;
      short8 pf = *reinterpret_cast<const short8*>(
          &Pw[((lr << 6) + ks2 * 32 + ((lane >> 4) << 3)) ^ ((lr & 7) << 3)]);
#pragma unroll
      for (int db = 0; db < 4; db++) {
        int dr = db * 16 + (lane & 15);
        short8 vf = *reinterpret_cast<const short8*>(
            &Vc[((dr << 6) + ks2 * 32 + ((lane >> 4) << 3)) ^ ((dr & 7) << 3)]);
        o[db] = __builtin_amdgcn_mfma_f32_16x16x32_bf16(pf, vf, o[db], 0, 0, 0);
      }
    }
  }

  // normalize + write attn out as bf16 [B,S,H*DK]
  float rl[4];
#pragma unroll
  for (int r = 0; r < 4; r++) rl[r] = __builtin_amdgcn_rcpf(l_[r]);
  const int lrb = (lane >> 4) << 2;
#pragma unroll
  for (int db = 0; db < 4; db++) {
#pragma unroll
    for (int r = 0; r < 4; r++) {
      int q = qrow_w + lrb + r;
      int d = db * 16 + (lane & 15);
      AO[((size_t)(b * SEQ + q)) * DMODEL + h * DK + d] = f2bf(o[db][r] * rl[r]);
    }
  }
}

extern "C" void kernel_launch(void* const* d_in, const int* in_sizes, int n_in,
                              void* d_out, int out_size, void* d_ws, size_t ws_size,
                              hipStream_t stream) {
  (void)in_sizes; (void)n_in; (void)out_size; (void)ws_size;
  const float* x     = (const float*)d_in[0];
  const float* w_qkv = (const float*)d_in[1];
  const float* b_qkv = (const float*)d_in[2];
  const float* w_out = (const float*)d_in[3];
  const float* b_out = (const float*)d_in[4];
  float* out = (float*)d_out;

  char* ws = (char*)d_ws;
  unsigned short* xb    = (unsigned short*)(ws);                    // 8 MB  [4096][1024]; reused as AOb
  unsigned short* wqkvb = (unsigned short*)(ws + (8u  << 20));      // 6 MB  [3072][1024]
  unsigned short* woutb = (unsigned short*)(ws + (14u << 20));      // 2 MB  [1024][1024]
  unsigned short* Qb    = (unsigned short*)(ws + (16u << 20));      // 8 MB  [32][2048][64] (pre-scaled)
  unsigned short* Kb    = (unsigned short*)(ws + (24u << 20));      // 8 MB  [32][2048][64]
  unsigned short* Vrow  = (unsigned short*)(ws + (32u << 20));      // 8 MB  [32][2048][64]
  unsigned short* Vtb   = (unsigned short*)(ws + (40u << 20));      // 8 MB  [32][64][2048]
  unsigned short* AOb   = xb;                                       // alias: xb dead after QKV GEMM

  f2bf_kernel<<<2048, 256, 0, stream>>>(x,     xb,    4194304 / 4);
  f2bf_kernel<<<2048, 256, 0, stream>>>(w_qkv, wqkvb, 3145728 / 4);
  f2bf_kernel<<<1024, 256, 0, stream>>>(w_out, woutb, 1048576 / 4);

  gemm_bt<0><<<dim3(32, 24), 256, 0, stream>>>(xb, wqkvb, b_qkv, nullptr,
                                               Qb, Kb, Vrow, 4096, 3072, 1024);

  transpose_v<<<dim3(32, 32), 256, 0, stream>>>(Vrow, Vtb);

  attn_kernel<<<dim3(32, 16), 512, 0, stream>>>(Qb, Kb, Vtb, AOb);

  gemm_bt<1><<<dim3(32, 8), 256, 0, stream>>>(AOb, woutb, b_out, out,
                                              nullptr, nullptr, nullptr, 4096, 1024, 1024);
}